// Round 9
// baseline (174.366 us; speedup 1.0000x reference)
//
#include <hip/hip_runtime.h>

#define BB   8
#define CC   64
#define HWN  19200
#define NPTS 12800
#define NSUB 3200
#define KNN  16
#define OUTN (HWN + NSUB)   // 22400

typedef __attribute__((ext_vector_type(8))) short short8;
typedef __attribute__((ext_vector_type(4))) float floatx4;

__device__ __forceinline__ unsigned short f2bf(float f) {
    union { float f; unsigned int i; } v; v.f = f;
    unsigned int r = v.i + 0x7fffu + ((v.i >> 16) & 1u);
    return (unsigned short)(r >> 16);
}
__device__ __forceinline__ float bf2f(unsigned short u) {
    union { unsigned int i; float f; } v; v.i = ((unsigned int)u) << 16; return v.f;
}

struct P {
    const float* pfeat; const float* rgb;
    const float* w0; const float* w1; const float* w2; const float* w3;
    const float* s_pp; const float* b_pp;
    const float* s_rp; const float* b_rp;
    const float* s_pf; const float* b_pf;
    const float* s_rf; const float* b_rf;
    const int* pool_idx; const int* p2r_idx; const int* r2p_idx;
    ushort* wB; ushort* pfT; ushort* rgbT;
    ushort* pe0T; ushort* p2rT; ushort* r2pT;
    float* out;
};

// ---------------------------------------------------------------------------
// K1: transpose f32 [B][C][N] -> bf16 [B][N][C], 128 n per block.
// Store side: ushort8 (16B/lane, 1KB/wave/instr, full 128B lines).
// grid 2096: w<800 pfeat (100 x 8), w<2000 rgb (150 x 8), w>=2000 weights.
// ---------------------------------------------------------------------------
__global__ __launch_bounds__(256) void k_p1(P p) {
    __shared__ ushort sm[2][64 * 65];
    int w = blockIdx.x, tid = threadIdx.x;
    if (w >= 2000) {              // weight cvt: 96 blocks x 256 = 24576 elems
        int i = (w - 2000) * 256 + tid;
        float v;
        if (i < 4096)       v = p.w0[i];
        else if (i < 8192)  v = p.w1[i - 4096];
        else if (i < 16384) v = p.w2[i - 8192];
        else                v = p.w3[i - 16384];
        p.wB[i] = f2bf(v);
        return;
    }
    bool isR = (w >= 800);
    int v0 = isR ? w - 800 : w;
    int b = v0 & 7, xx = v0 >> 3;          // pf 0..99 / rgb 0..149
    const float* src = (isR ? p.rgb : p.pfeat);
    ushort* outp     = (isR ? p.rgbT : p.pfT);
    int N  = isR ? HWN : NPTS;
    int n0 = xx * 128;
    src += (size_t)b * CC * N + n0;

    int l = tid & 15, ch = tid >> 4;
    float4 v[2][4];
    #pragma unroll
    for (int s = 0; s < 2; ++s)
        #pragma unroll
        for (int it = 0; it < 4; ++it)
            v[s][it] = *(const float4*)(src + (size_t)(ch + 16 * it) * N + s * 64 + 4 * l);
    #pragma unroll
    for (int s = 0; s < 2; ++s)
        #pragma unroll
        for (int it = 0; it < 4; ++it) {
            int c = ch + 16 * it;
            sm[s][c * 65 + 4 * l + 0] = f2bf(v[s][it].x);
            sm[s][c * 65 + 4 * l + 1] = f2bf(v[s][it].y);
            sm[s][c * 65 + 4 * l + 2] = f2bf(v[s][it].z);
            sm[s][c * 65 + 4 * l + 3] = f2bf(v[s][it].w);
        }
    __syncthreads();
    // store: lane owns 8 channels (c8) of one n-row -> ushort8 (16B)
    ushort* dst = outp + ((size_t)b * N + n0) * CC;
    int c8 = (tid & 7) * 8;
    #pragma unroll
    for (int pass = 0; pass < 4; ++pass) {
        int n_loc = (tid >> 3) + 32 * pass;    // 0..127
        int s = n_loc >> 6, n = n_loc & 63;
        short8 r;
        #pragma unroll
        for (int u = 0; u < 8; ++u)
            r[u] = (short)sm[s][(c8 + u) * 65 + n];
        *(short8*)(dst + (size_t)n_loc * CC + c8) = r;
    }
}

// ---------------------------------------------------------------------------
// K2: gather + maxpool + pre-conv GEMM, ZERO LDS / ZERO barriers.
// Lane (l15,quad) gathers point m=m0+wave*16+l15, channels quad*8.. and
// 32+quad*8.. (two short8 per neighbor) -> maxpool lands directly in the
// MFMA A-fragment registers. o-interleaved B-tiles (tile t: o=4*l15+t) ->
// epilogue is 4 ushort4 stores (512B/wave/instr).
// grid 800: w<400 point-stream, else rgb-stream; 64 points per block.
// ---------------------------------------------------------------------------
__global__ __launch_bounds__(256) void k_p2(P p) {
    int w = blockIdx.x, tid = threadIdx.x;
    bool pt = (w < 400);
    int v0 = pt ? w : w - 400;
    int b = v0 & 7, xx = v0 >> 3;     // xx 0..49
    int m0 = xx * 64;
    const ushort* xT  = pt ? p.pfT : p.rgbT;
    const int*    idx = pt ? p.pool_idx : p.r2p_idx;
    int Nin           = pt ? NPTS : HWN;
    const ushort* W   = pt ? p.wB : p.wB + 4096;   // [64][64]
    const float*  sv  = pt ? p.s_pp : p.s_rp;
    const float*  bv  = pt ? p.b_pp : p.b_rp;
    ushort*       dst = pt ? p.p2rT : p.r2pT;

    int wave = tid >> 6, lane = tid & 63;
    int l15 = lane & 15, quad = lane >> 4;
    int m = m0 + wave * 16 + l15;

    const int4* ip4 = (const int4*)(idx + ((size_t)b * NSUB + m) * KNN);
    int4 q0 = ip4[0], q1 = ip4[1], q2 = ip4[2], q3 = ip4[3];
    int js[16] = { q0.x, q0.y, q0.z, q0.w, q1.x, q1.y, q1.z, q1.w,
                   q2.x, q2.y, q2.z, q2.w, q3.x, q3.y, q3.z, q3.w };
    const ushort* xb = xT + (size_t)b * Nin * CC;
    int c_lo = quad * 8, c_hi = 32 + quad * 8;

    float alo[8], ahi[8];
    #pragma unroll
    for (int u = 0; u < 8; ++u) { alo[u] = -1e30f; ahi[u] = -1e30f; }
    #pragma unroll
    for (int k = 0; k < KNN; ++k) {
        const ushort* row = xb + (size_t)js[k] * CC;
        short8 vlo = *(const short8*)(row + c_lo);
        short8 vhi = *(const short8*)(row + c_hi);
        #pragma unroll
        for (int u = 0; u < 8; ++u) {
            alo[u] = fmaxf(alo[u], bf2f((unsigned short)vlo[u]));
            ahi[u] = fmaxf(ahi[u], bf2f((unsigned short)vhi[u]));
        }
    }
    short8 flo, fhi;
    #pragma unroll
    for (int u = 0; u < 8; ++u) {
        flo[u] = (short)f2bf(alo[u]);
        fhi[u] = (short)f2bf(ahi[u]);
    }
    if (pt) {   // pe0T reused by k_p3 point-path
        ushort* pr = p.pe0T + ((size_t)b * NSUB + m) * CC;
        *(short8*)(pr + c_lo) = flo;
        *(short8*)(pr + c_hi) = fhi;
    }

    // pre-conv GEMM: D = X(A rows=m, frags in regs) * W^T(B cols o=4*l15+t)
    floatx4 acc[4] = {{0.f,0.f,0.f,0.f},{0.f,0.f,0.f,0.f},{0.f,0.f,0.f,0.f},{0.f,0.f,0.f,0.f}};
    #pragma unroll
    for (int t = 0; t < 4; ++t) {
        int o = 4 * l15 + t;
        short8 wlo = *(const short8*)(W + (size_t)o * CC + quad * 8);
        short8 whi = *(const short8*)(W + (size_t)o * CC + 32 + quad * 8);
        acc[t] = __builtin_amdgcn_mfma_f32_16x16x32_bf16(flo, wlo, acc[t], 0, 0, 0);
        acc[t] = __builtin_amdgcn_mfma_f32_16x16x32_bf16(fhi, whi, acc[t], 0, 0, 0);
    }

    float4 svv = *(const float4*)(sv + 4 * l15);
    float4 bvv = *(const float4*)(bv + 4 * l15);
    float ssv[4] = { svv.x, svv.y, svv.z, svv.w };
    float bbv[4] = { bvv.x, bvv.y, bvv.z, bvv.w };
    #pragma unroll
    for (int r = 0; r < 4; ++r) {
        int n = m0 + wave * 16 + quad * 4 + r;
        ushort4 st;
        unsigned short e[4];
        #pragma unroll
        for (int t = 0; t < 4; ++t)
            e[t] = f2bf(fmaxf(acc[t][r] * ssv[t] + bbv[t], 0.f));
        st.x = e[0]; st.y = e[1]; st.z = e[2]; st.w = e[3];
        *(ushort4*)(dst + ((size_t)b * NSUB + n) * CC + 4 * l15) = st;
    }
}

// ---------------------------------------------------------------------------
// K3 (frozen): both fuse GEMMs -> d_out. D = W(A rows=o) * X(B cols=n), K=128.
// ---------------------------------------------------------------------------
__global__ __launch_bounds__(256) void k_p3(P p) {
    int w = blockIdx.x, tid = threadIdx.x;
    bool rp = (w < 600);
    int v0 = rp ? w : w - 600;
    int b = v0 & 7, x0 = v0 >> 3;     // rgb 0..74 / pt 0..12
    const ushort* x1T = rp ? p.rgbT : p.pe0T;
    const ushort* x2T = rp ? p.p2rT : p.r2pT;
    int N             = rp ? HWN : NSUB;
    int pos0          = rp ? 0 : HWN;
    const ushort* W   = rp ? p.wB + 8192 : p.wB + 16384;   // [64][128]
    const float*  sv  = rp ? p.s_pf : p.s_rf;
    const float*  bv  = rp ? p.b_pf : p.b_rf;

    int wave = tid >> 6, lane = tid & 63;
    int l15 = lane & 15, quad = lane >> 4;
    int n_base = x0 * 256 + wave * 64;
    int ncol   = n_base + l15 * 4;
    bool act   = rp || (ncol < NSUB);
    int nc     = act ? ncol : 0;

    const ushort* r1[4];
    const ushort* r2[4];
    if (rp) {
        int4 i4 = *(const int4*)(p.p2r_idx + (size_t)b * N + nc);
        int n2s[4] = { i4.x, i4.y, i4.z, i4.w };
        #pragma unroll
        for (int g = 0; g < 4; ++g) {
            r1[g] = x1T + ((size_t)b * N + nc + g) * CC + quad * 8;
            r2[g] = x2T + ((size_t)b * NSUB + n2s[g]) * CC + quad * 8;
        }
    } else {
        #pragma unroll
        for (int g = 0; g < 4; ++g) {
            r1[g] = x1T + ((size_t)b * N + nc + g) * CC + quad * 8;
            r2[g] = x2T + ((size_t)b * NSUB + nc + g) * CC + quad * 8;
        }
    }

    floatx4 acc[4][4];   // [g][t]
    #pragma unroll
    for (int g = 0; g < 4; ++g)
        #pragma unroll
        for (int t = 0; t < 4; ++t)
            acc[g][t] = floatx4{0.f, 0.f, 0.f, 0.f};

    #pragma unroll
    for (int kk = 0; kk < 4; ++kk) {
        short8 xf[4];
        #pragma unroll
        for (int g = 0; g < 4; ++g)
            xf[g] = (kk < 2) ? *(const short8*)(r1[g] + kk * 32)
                             : *(const short8*)(r2[g] + (kk - 2) * 32);
        #pragma unroll
        for (int t = 0; t < 4; ++t) {
            short8 wf = *(const short8*)(W + (size_t)(t * 16 + l15) * 128 + kk * 32 + quad * 8);
            #pragma unroll
            for (int g = 0; g < 4; ++g)
                acc[g][t] = __builtin_amdgcn_mfma_f32_16x16x32_bf16(wf, xf[g], acc[g][t], 0, 0, 0);
        }
    }

    #pragma unroll
    for (int t = 0; t < 4; ++t) {
        #pragma unroll
        for (int r = 0; r < 4; ++r) {
            int o = t * 16 + quad * 4 + r;
            float ss = sv[o], bb2 = bv[o];
            float4 y;
            y.x = fmaxf(acc[0][t][r] * ss + bb2, 0.f);
            y.y = fmaxf(acc[1][t][r] * ss + bb2, 0.f);
            y.z = fmaxf(acc[2][t][r] * ss + bb2, 0.f);
            y.w = fmaxf(acc[3][t][r] * ss + bb2, 0.f);
            if (act)
                *(float4*)(p.out + ((size_t)b * CC + o) * OUTN + pos0 + nc) = y;
        }
    }
}

extern "C" void kernel_launch(void* const* d_in, const int* in_sizes, int n_in,
                              void* d_out, int out_size, void* d_ws, size_t ws_size,
                              hipStream_t stream) {
    char* ws = (char*)d_ws;
    ushort* wB   = (ushort*)ws; ws += 24576 * 2;
    ushort* pfT  = (ushort*)ws; ws += (size_t)BB * NPTS * CC * 2;
    ushort* rgbT = (ushort*)ws; ws += (size_t)BB * HWN  * CC * 2;
    ushort* pe0T = (ushort*)ws; ws += (size_t)BB * NSUB * CC * 2;
    ushort* p2rT = (ushort*)ws; ws += (size_t)BB * NSUB * CC * 2;
    ushort* r2pT = (ushort*)ws; ws += (size_t)BB * NSUB * CC * 2;

    P p;
    p.pfeat = (const float*)d_in[1];
    p.rgb   = (const float*)d_in[0];
    p.w0    = (const float*)d_in[2];
    p.w1    = (const float*)d_in[8];
    p.w2    = (const float*)d_in[5];
    p.w3    = (const float*)d_in[11];
    p.s_pp  = (const float*)d_in[3];   p.b_pp = (const float*)d_in[4];
    p.s_rp  = (const float*)d_in[9];   p.b_rp = (const float*)d_in[10];
    p.s_pf  = (const float*)d_in[6];   p.b_pf = (const float*)d_in[7];
    p.s_rf  = (const float*)d_in[12];  p.b_rf = (const float*)d_in[13];
    p.pool_idx = (const int*)d_in[14];
    p.p2r_idx  = (const int*)d_in[15];
    p.r2p_idx  = (const int*)d_in[16];
    p.wB = wB; p.pfT = pfT; p.rgbT = rgbT;
    p.pe0T = pe0T; p.p2rT = p2rT; p.r2pT = r2pT;
    p.out = (float*)d_out;

    k_p1<<<dim3(2096), 256, 0, stream>>>(p);
    k_p2<<<dim3(800),  256, 0, stream>>>(p);
    k_p3<<<dim3(704),  256, 0, stream>>>(p);
}

// Round 11
// 167.984 us; speedup vs baseline: 1.0380x; 1.0380x over previous
//
#include <hip/hip_runtime.h>

#define BB   8
#define CC   64
#define HWN  19200
#define NPTS 12800
#define NSUB 3200
#define KNN  16
#define OUTN (HWN + NSUB)   // 22400

typedef __attribute__((ext_vector_type(8))) short short8;
typedef __attribute__((ext_vector_type(4))) float floatx4;

__device__ __forceinline__ unsigned short f2bf(float f) {
    union { float f; unsigned int i; } v; v.f = f;
    unsigned int r = v.i + 0x7fffu + ((v.i >> 16) & 1u);
    return (unsigned short)(r >> 16);
}
__device__ __forceinline__ float bf2f(unsigned short u) {
    union { unsigned int i; float f; } v; v.i = ((unsigned int)u) << 16; return v.f;
}

struct P {
    const float* pfeat; const float* rgb;
    const float* w0; const float* w1; const float* w2; const float* w3;
    const float* s_pp; const float* b_pp;
    const float* s_rp; const float* b_rp;
    const float* s_pf; const float* b_pf;
    const float* s_rf; const float* b_rf;
    const int* pool_idx; const int* p2r_idx; const int* r2p_idx;
    ushort* wB; ushort* pfT; ushort* rgbT;
    ushort* pe0T; ushort* p2rT; ushort* r2pT;
    float* out;
};

// ---------------------------------------------------------------------------
// K1 (frozen, R8): transpose f32 [B][C][N] -> bf16 [B][N][C], 128 n/block,
// float4 loads, ushort8 stores. grid 2096.
// ---------------------------------------------------------------------------
__global__ __launch_bounds__(256) void k_p1(P p) {
    __shared__ ushort sm[2][64 * 65];
    int w = blockIdx.x, tid = threadIdx.x;
    if (w >= 2000) {
        int i = (w - 2000) * 256 + tid;
        float v;
        if (i < 4096)       v = p.w0[i];
        else if (i < 8192)  v = p.w1[i - 4096];
        else if (i < 16384) v = p.w2[i - 8192];
        else                v = p.w3[i - 16384];
        p.wB[i] = f2bf(v);
        return;
    }
    bool isR = (w >= 800);
    int v0 = isR ? w - 800 : w;
    int b = v0 & 7, xx = v0 >> 3;
    const float* src = (isR ? p.rgb : p.pfeat);
    ushort* outp     = (isR ? p.rgbT : p.pfT);
    int N  = isR ? HWN : NPTS;
    int n0 = xx * 128;
    src += (size_t)b * CC * N + n0;

    int l = tid & 15, ch = tid >> 4;
    float4 v[2][4];
    #pragma unroll
    for (int s = 0; s < 2; ++s)
        #pragma unroll
        for (int it = 0; it < 4; ++it)
            v[s][it] = *(const float4*)(src + (size_t)(ch + 16 * it) * N + s * 64 + 4 * l);
    #pragma unroll
    for (int s = 0; s < 2; ++s)
        #pragma unroll
        for (int it = 0; it < 4; ++it) {
            int c = ch + 16 * it;
            sm[s][c * 65 + 4 * l + 0] = f2bf(v[s][it].x);
            sm[s][c * 65 + 4 * l + 1] = f2bf(v[s][it].y);
            sm[s][c * 65 + 4 * l + 2] = f2bf(v[s][it].z);
            sm[s][c * 65 + 4 * l + 3] = f2bf(v[s][it].w);
        }
    __syncthreads();
    ushort* dst = outp + ((size_t)b * N + n0) * CC;
    int c8 = (tid & 7) * 8;
    #pragma unroll
    for (int pass = 0; pass < 4; ++pass) {
        int n_loc = (tid >> 3) + 32 * pass;
        int s = n_loc >> 6, n = n_loc & 63;
        short8 r;
        #pragma unroll
        for (int u = 0; u < 8; ++u)
            r[u] = (short)sm[s][(c8 + u) * 65 + n];
        *(short8*)(dst + (size_t)n_loc * CC + c8) = r;
    }
}

// ---------------------------------------------------------------------------
// K2 (frozen, R8): gather + maxpool + pre-conv GEMM. grid 800.
// ---------------------------------------------------------------------------
__global__ __launch_bounds__(256) void k_p2(P p) {
    __shared__ ushort sm[64 * 72];
    int w = blockIdx.x, tid = threadIdx.x;
    bool pt = (w < 400);
    int v0 = pt ? w : w - 400;
    int b = v0 & 7, xx = v0 >> 3;
    int m0 = xx * 64;
    const ushort* xT  = pt ? p.pfT : p.rgbT;
    const int*    idx = pt ? p.pool_idx : p.r2p_idx;
    int Nin           = pt ? NPTS : HWN;
    const ushort* W   = pt ? p.wB : p.wB + 4096;   // [64][64]
    const float*  sv  = pt ? p.s_pp : p.s_rp;
    const float*  bv  = pt ? p.b_pp : p.b_rp;
    ushort*       dst = pt ? p.p2rT : p.r2pT;

    int c8   = (tid & 7) * 8;
    int mloc = tid >> 3;          // 0..31: 32 points per pass
    const ushort* xb = xT + (size_t)b * Nin * CC + c8;
    #pragma unroll
    for (int pass = 0; pass < 2; ++pass) {
        int ml = mloc + pass * 32;
        int m  = m0 + ml;
        const int4* ip4 = (const int4*)(idx + ((size_t)b * NSUB + m) * KNN);
        int4 q0 = ip4[0], q1 = ip4[1], q2 = ip4[2], q3 = ip4[3];
        int js[16] = { q0.x, q0.y, q0.z, q0.w, q1.x, q1.y, q1.z, q1.w,
                       q2.x, q2.y, q2.z, q2.w, q3.x, q3.y, q3.z, q3.w };
        float a[8];
        #pragma unroll
        for (int u = 0; u < 8; ++u) a[u] = -1e30f;
        #pragma unroll
        for (int k = 0; k < KNN; ++k) {
            short8 val = *(const short8*)(xb + (size_t)js[k] * CC);
            #pragma unroll
            for (int u = 0; u < 8; ++u)
                a[u] = fmaxf(a[u], bf2f((unsigned short)val[u]));
        }
        short8 r;
        #pragma unroll
        for (int u = 0; u < 8; ++u) r[u] = (short)f2bf(a[u]);
        *(short8*)(&sm[ml * 72 + c8]) = r;
        if (pt)
            *(short8*)(p.pe0T + ((size_t)b * NSUB + m) * CC + c8) = r;
    }
    __syncthreads();
    int wave = tid >> 6, lane = tid & 63;
    int l15 = lane & 15, quad = lane >> 4;
    int nloc0 = wave * 16;
    floatx4 acc[4] = {{0.f,0.f,0.f,0.f},{0.f,0.f,0.f,0.f},{0.f,0.f,0.f,0.f},{0.f,0.f,0.f,0.f}};
    #pragma unroll
    for (int kk = 0; kk < 2; ++kk) {
        short8 a = *(const short8*)(&sm[(nloc0 + l15) * 72 + kk * 32 + quad * 8]);
        #pragma unroll
        for (int t = 0; t < 4; ++t) {
            short8 wf = *(const short8*)(W + (size_t)(t * 16 + l15) * CC + kk * 32 + quad * 8);
            acc[t] = __builtin_amdgcn_mfma_f32_16x16x32_bf16(a, wf, acc[t], 0, 0, 0);
        }
    }
    #pragma unroll
    for (int t = 0; t < 4; ++t) {
        int o = t * 16 + l15;
        float ss = sv[o], bb2 = bv[o];
        #pragma unroll
        for (int r = 0; r < 4; ++r) {
            int n = m0 + nloc0 + quad * 4 + r;
            float y = fmaxf(acc[t][r] * ss + bb2, 0.f);
            dst[((size_t)b * NSUB + n) * CC + o] = f2bf(y);
        }
    }
}

// ---------------------------------------------------------------------------
// K3 (restructured): both fuse GEMMs -> d_out. D = W(A rows=o)*X(B cols=n),
// K=128. All 16 B-fragments PRELOADED (one waitcnt), then per o-tile t:
// 16 MFMA followed immediately by t's 4 nontemporal floatx4 stores, so the
// store pipe overlaps the next tile's compute instead of bursting at the end.
// grid 704: w<600 rgb-path, else point-path (guarded).
// ---------------------------------------------------------------------------
__global__ __launch_bounds__(256) void k_p3(P p) {
    int w = blockIdx.x, tid = threadIdx.x;
    bool rp = (w < 600);
    int v0 = rp ? w : w - 600;
    int b = v0 & 7, x0 = v0 >> 3;     // rgb 0..74 / pt 0..12
    const ushort* x1T = rp ? p.rgbT : p.pe0T;
    const ushort* x2T = rp ? p.p2rT : p.r2pT;
    int N             = rp ? HWN : NSUB;
    int pos0          = rp ? 0 : HWN;
    const ushort* W   = rp ? p.wB + 8192 : p.wB + 16384;   // [64][128]
    const float*  sv  = rp ? p.s_pf : p.s_rf;
    const float*  bv  = rp ? p.b_pf : p.b_rf;

    int wave = tid >> 6, lane = tid & 63;
    int l15 = lane & 15, quad = lane >> 4;
    int n_base = x0 * 256 + wave * 64;
    int ncol   = n_base + l15 * 4;
    bool act   = rp || (ncol < NSUB);
    int nc     = act ? ncol : 0;

    // preload all B-fragments: xf[kk][g], 16 independent 16B loads
    short8 xf[4][4];
    {
        const ushort* r1[4];
        const ushort* r2[4];
        if (rp) {
            int4 i4 = *(const int4*)(p.p2r_idx + (size_t)b * N + nc);
            int n2s[4] = { i4.x, i4.y, i4.z, i4.w };
            #pragma unroll
            for (int g = 0; g < 4; ++g) {
                r1[g] = x1T + ((size_t)b * N + nc + g) * CC + quad * 8;
                r2[g] = x2T + ((size_t)b * NSUB + n2s[g]) * CC + quad * 8;
            }
        } else {
            #pragma unroll
            for (int g = 0; g < 4; ++g) {
                r1[g] = x1T + ((size_t)b * N + nc + g) * CC + quad * 8;
                r2[g] = x2T + ((size_t)b * NSUB + nc + g) * CC + quad * 8;
            }
        }
        #pragma unroll
        for (int g = 0; g < 4; ++g) {
            xf[0][g] = *(const short8*)(r1[g]);
            xf[1][g] = *(const short8*)(r1[g] + 32);
            xf[2][g] = *(const short8*)(r2[g]);
            xf[3][g] = *(const short8*)(r2[g] + 32);
        }
    }

    float* outb = p.out + (size_t)b * CC * OUTN + pos0 + nc;
    #pragma unroll
    for (int t = 0; t < 4; ++t) {
        floatx4 acc[4] = {{0.f,0.f,0.f,0.f},{0.f,0.f,0.f,0.f},
                          {0.f,0.f,0.f,0.f},{0.f,0.f,0.f,0.f}};
        #pragma unroll
        for (int kk = 0; kk < 4; ++kk) {
            short8 wf = *(const short8*)(W + (size_t)(t * 16 + l15) * 128 + kk * 32 + quad * 8);
            #pragma unroll
            for (int g = 0; g < 4; ++g)
                acc[g] = __builtin_amdgcn_mfma_f32_16x16x32_bf16(wf, xf[kk][g], acc[g], 0, 0, 0);
        }
        // store tile t immediately: overlaps next tile's MFMA
        #pragma unroll
        for (int r = 0; r < 4; ++r) {
            int o = t * 16 + quad * 4 + r;
            float ss = sv[o], bb2 = bv[o];
            floatx4 y;
            y[0] = fmaxf(acc[0][r] * ss + bb2, 0.f);
            y[1] = fmaxf(acc[1][r] * ss + bb2, 0.f);
            y[2] = fmaxf(acc[2][r] * ss + bb2, 0.f);
            y[3] = fmaxf(acc[3][r] * ss + bb2, 0.f);
            if (act)
                __builtin_nontemporal_store(y, (floatx4*)(outb + (size_t)o * OUTN));
        }
    }
}

extern "C" void kernel_launch(void* const* d_in, const int* in_sizes, int n_in,
                              void* d_out, int out_size, void* d_ws, size_t ws_size,
                              hipStream_t stream) {
    char* ws = (char*)d_ws;
    ushort* wB   = (ushort*)ws; ws += 24576 * 2;
    ushort* pfT  = (ushort*)ws; ws += (size_t)BB * NPTS * CC * 2;
    ushort* rgbT = (ushort*)ws; ws += (size_t)BB * HWN  * CC * 2;
    ushort* pe0T = (ushort*)ws; ws += (size_t)BB * NSUB * CC * 2;
    ushort* p2rT = (ushort*)ws; ws += (size_t)BB * NSUB * CC * 2;
    ushort* r2pT = (ushort*)ws; ws += (size_t)BB * NSUB * CC * 2;

    P p;
    p.pfeat = (const float*)d_in[1];
    p.rgb   = (const float*)d_in[0];
    p.w0    = (const float*)d_in[2];
    p.w1    = (const float*)d_in[8];
    p.w2    = (const float*)d_in[5];
    p.w3    = (const float*)d_in[11];
    p.s_pp  = (const float*)d_in[3];   p.b_pp = (const float*)d_in[4];
    p.s_rp  = (const float*)d_in[9];   p.b_rp = (const float*)d_in[10];
    p.s_pf  = (const float*)d_in[6];   p.b_pf = (const float*)d_in[7];
    p.s_rf  = (const float*)d_in[12];  p.b_rf = (const float*)d_in[13];
    p.pool_idx = (const int*)d_in[14];
    p.p2r_idx  = (const int*)d_in[15];
    p.r2p_idx  = (const int*)d_in[16];
    p.wB = wB; p.pfT = pfT; p.rgbT = rgbT;
    p.pe0T = pe0T; p.p2rT = p2rT; p.r2pT = r2pT;
    p.out = (float*)d_out;

    k_p1<<<dim3(2096), 256, 0, stream>>>(p);
    k_p2<<<dim3(800),  256, 0, stream>>>(p);
    k_p3<<<dim3(704),  256, 0, stream>>>(p);
}